// Round 6
// baseline (31.082 us; speedup 1.0000x reference)
//
#include <hip/hip_runtime.h>
#include <math.h>

#define BLOCK 256
#define MAXT  64

// One thread per (b, a). 1536 blocks -> 6 blocks/CU, 24 waves/CU target occupancy.
// Division-free assignment:
//   iou = n/(d-n), n=inter, d=area_a+area_t, monotone in n/d =>
//   ratio compare via cross-mult; max_iou > 0.5 <=> 3*n_best > d_best.
// Argmax over T=64 is a chunked TREE (8 chunks x depth-3 + 1 merge): the 8
// (n,d) candidates per chunk are independent (ILP), so the serial dependent
// chain shrinks from 64 compare-selects to ~11. First-max semantics: the left
// operand of every compare carries the smaller index and is replaced only on
// strict '>'.
__global__ void __launch_bounds__(BLOCK)
rpn_main(const float* __restrict__ reg,
         const float* __restrict__ cls,
         const float* __restrict__ anchors,
         const float* __restrict__ targets,
         float* __restrict__ partials,   // SoA: [3][nblk]
         int A, int B, int T, int nblk) {
    const int blocksPerB = A / BLOCK;               // exact for this shape
    const int b = blockIdx.x / blocksPerB;
    const int a = (blockIdx.x - b * blocksPerB) * BLOCK + threadIdx.x;

    __shared__ float4 s_box[MAXT];
    if (threadIdx.x < T)
        s_box[threadIdx.x] = reinterpret_cast<const float4*>(targets)[b * T + threadIdx.x];
    __syncthreads();

    const float4 A0 = reinterpret_cast<const float4*>(anchors)[a];
    const float  sa = (A0.z - A0.x) * (A0.w - A0.y);

    // hoisted cls + stable softplus (matches jax.nn.softplus)
    const int   base = b * A;
    const float c0   = cls[base + a];
    const float sp0  = fmaxf(c0, 0.f) + log1pf(expf(-fabsf(c0)));

    float bn = 0.f, bd = 1.f;
    int   bt = 0;

    if (T == 64) {
        #pragma unroll 2
        for (int c = 0; c < 64; c += 8) {
            // 8 independent candidates (pure ILP, ds_read_b128 broadcast)
            float n[8], d[8];
            #pragma unroll
            for (int j = 0; j < 8; ++j) {
                const float4 tb = s_box[c + j];
                const float st = (tb.z - tb.x) * (tb.w - tb.y);
                const float iw = fmaxf(fminf(tb.z, A0.z) - fmaxf(tb.x, A0.x), 0.f);
                const float ih = fmaxf(fminf(tb.w, A0.w) - fmaxf(tb.y, A0.y), 0.f);
                n[j] = iw * ih;
                d[j] = sa + st;
            }
            // depth-3 tree; left always smaller index, replace on strict >
            float wn[4], wd[4]; int wi[4];
            #pragma unroll
            for (int j = 0; j < 4; ++j) {
                const bool up = n[2*j+1] * d[2*j] > n[2*j] * d[2*j+1];
                wn[j] = up ? n[2*j+1] : n[2*j];
                wd[j] = up ? d[2*j+1] : d[2*j];
                wi[j] = up ? c + 2*j + 1 : c + 2*j;
            }
            float xn[2], xd[2]; int xi[2];
            #pragma unroll
            for (int j = 0; j < 2; ++j) {
                const bool up = wn[2*j+1] * wd[2*j] > wn[2*j] * wd[2*j+1];
                xn[j] = up ? wn[2*j+1] : wn[2*j];
                xd[j] = up ? wd[2*j+1] : wd[2*j];
                xi[j] = up ? wi[2*j+1] : wi[2*j];
            }
            const bool u2 = xn[1] * xd[0] > xn[0] * xd[1];
            const float cn = u2 ? xn[1] : xn[0];
            const float cd = u2 ? xd[1] : xd[0];
            const int   ci = u2 ? xi[1] : xi[0];
            // merge with running best (chunk indices all larger than bt)
            const bool um = cn * bd > bn * cd;
            bn = um ? cn : bn;
            bd = um ? cd : bd;
            bt = um ? ci : bt;
        }
    } else {
        for (int t = 0; t < T; ++t) {
            const float4 tb = s_box[t];
            const float st = (tb.z - tb.x) * (tb.w - tb.y);
            const float iw = fmaxf(fminf(tb.z, A0.z) - fmaxf(tb.x, A0.x), 0.f);
            const float ih = fmaxf(fminf(tb.w, A0.w) - fmaxf(tb.y, A0.y), 0.f);
            const float n = iw * ih, d = sa + st;
            if (n * bd > bn * d) { bn = n; bd = d; bt = t; }
        }
    }

    const float pos = (3.f * bn > bd) ? 1.f : 0.f;
    float bce  = sp0 - c0 * pos;
    float npos = pos;
    float sl1  = 0.f;

    if (pos != 0.f) {
        const float4 r  = reinterpret_cast<const float4*>(reg)[base + a];
        const float4 tb = s_box[bt];
        float e, ae;
        e = r.x - (tb.x - A0.x); ae = fabsf(e); sl1 += (ae < 1.f) ? 0.5f * e * e : ae - 0.5f;
        e = r.y - (tb.y - A0.y); ae = fabsf(e); sl1 += (ae < 1.f) ? 0.5f * e * e : ae - 0.5f;
        e = r.z - (tb.z - A0.z); ae = fabsf(e); sl1 += (ae < 1.f) ? 0.5f * e * e : ae - 0.5f;
        e = r.w - (tb.w - A0.w); ae = fabsf(e); sl1 += (ae < 1.f) ? 0.5f * e * e : ae - 0.5f;
    }

    // deterministic block reduction: wave64 shuffle then cross-wave LDS
    for (int off = 32; off > 0; off >>= 1) {
        bce  += __shfl_down(bce,  off, 64);
        sl1  += __shfl_down(sl1,  off, 64);
        npos += __shfl_down(npos, off, 64);
    }
    __shared__ float w_bce[BLOCK / 64], w_sl1[BLOCK / 64], w_np[BLOCK / 64];
    const int lane = threadIdx.x & 63, wid = threadIdx.x >> 6;
    if (lane == 0) { w_bce[wid] = bce; w_sl1[wid] = sl1; w_np[wid] = npos; }
    __syncthreads();
    if (threadIdx.x == 0) {
        float tb_ = 0.f, ts_ = 0.f, tn_ = 0.f;
        for (int w = 0; w < BLOCK / 64; ++w) {
            tb_ += w_bce[w]; ts_ += w_sl1[w]; tn_ += w_np[w];
        }
        partials[0 * nblk + blockIdx.x] = tb_;
        partials[1 * nblk + blockIdx.x] = ts_;
        partials[2 * nblk + blockIdx.x] = tn_;
    }
}

// Final reduce: ONE wave, pure double shuffle reduction, no __syncthreads.
__global__ void __launch_bounds__(64)
rpn_final(const float* __restrict__ partials, int nblk,
          float* __restrict__ out, int BA) {
    double b = 0.0, s = 0.0, n = 0.0;
    for (int i = threadIdx.x; i < nblk; i += 64) {
        b += (double)partials[0 * nblk + i];
        s += (double)partials[1 * nblk + i];
        n += (double)partials[2 * nblk + i];
    }
    for (int off = 32; off > 0; off >>= 1) {
        b += __shfl_down(b, off, 64);
        s += __shfl_down(s, off, 64);
        n += __shfl_down(n, off, 64);
    }
    if (threadIdx.x == 0) {
        const double denom = n > 1.0 ? n : 1.0;
        const double reg_loss = (n > 0.0) ? (s / denom) : 0.0;
        out[0] = (float)(b / (double)BA);     // cls_loss (mean BCE)
        out[1] = (float)(reg_loss * 0.25);    // reg_loss / 4
    }
}

extern "C" void kernel_launch(void* const* d_in, const int* in_sizes, int n_in,
                              void* d_out, int out_size, void* d_ws, size_t ws_size,
                              hipStream_t stream) {
    const float* reg     = (const float*)d_in[0];
    const float* cls     = (const float*)d_in[1];
    const float* anchors = (const float*)d_in[2];
    const float* targets = (const float*)d_in[3];
    float* out = (float*)d_out;

    const int A = in_sizes[2] / 4;          // anchors [A,4]
    const int B = in_sizes[1] / A;          // cls [B,A]
    const int T = in_sizes[3] / (B * 4);    // targets [B,T,4]
    const int BA = B * A;
    const int nblk = BA / BLOCK;            // 1536 -> 6 blocks/CU

    float* partials = (float*)d_ws;         // SoA [3][nblk], fully overwritten every call

    rpn_main<<<nblk, BLOCK, 0, stream>>>(reg, cls, anchors, targets,
                                         partials, A, B, T, nblk);
    rpn_final<<<1, 64, 0, stream>>>(partials, nblk, out, BA);
}

// Round 7
// 26.061 us; speedup vs baseline: 1.1927x; 1.1927x over previous
//
#include <hip/hip_runtime.h>
#include <math.h>

#define BLOCK 256
#define MAXT  64
#define NA    6    // anchors per thread: A/NA = 16384 -> 256 blocks = 1/CU

// One thread handles NA=6 anchors (q + j*A/NA) of one batch b.
// 256 blocks -> exactly 1 block/CU, 4 waves/CU. The per-t shared work
// (broadcast ds_read_b128 + target area) is amortized over 6 anchors, cutting
// per-CU wave-iterations 3x vs the 2-anchor variant (the quantity that has
// tracked duration across rounds 1-6). Six independent compare-select chains
// provide the ILP to hide LDS latency at 1 wave/SIMD.
// Division-free assignment: iou = n/(d-n) monotone in n/d => cross-mult
// compare (strict > == first-max argmax); max_iou > 0.5 <=> 3*n > d.
__global__ void __launch_bounds__(BLOCK)
rpn_main(const float* __restrict__ reg,
         const float* __restrict__ cls,
         const float* __restrict__ anchors,
         const float* __restrict__ targets,
         float* __restrict__ partials,   // SoA: [3][nblk]
         int A, int B, int T, int nblk) {
    const int S = A / NA;                        // 16384
    const int blocksPerB = S / BLOCK;            // 64 (exact for this shape)
    const int b = blockIdx.x / blocksPerB;
    const int q = (blockIdx.x - b * blocksPerB) * BLOCK + threadIdx.x;

    __shared__ float4 s_box[MAXT];
    if (threadIdx.x < T)
        s_box[threadIdx.x] = reinterpret_cast<const float4*>(targets)[b * T + threadIdx.x];
    __syncthreads();

    const int base = b * A;

    float4 Ax[NA];
    float  sa[NA], cv[NA], sp[NA];
    #pragma unroll
    for (int j = 0; j < NA; ++j) {
        const int a = q + j * S;
        Ax[j] = reinterpret_cast<const float4*>(anchors)[a];
        sa[j] = (Ax[j].z - Ax[j].x) * (Ax[j].w - Ax[j].y);
        cv[j] = cls[base + a];
        // stable softplus, matches jax.nn.softplus
        sp[j] = fmaxf(cv[j], 0.f) + log1pf(expf(-fabsf(cv[j])));
    }

    float bn[NA], bd[NA];
    int   bt[NA];
    #pragma unroll
    for (int j = 0; j < NA; ++j) { bn[j] = 0.f; bd[j] = 1.f; bt[j] = 0; }

    #pragma unroll 4
    for (int t = 0; t < T; ++t) {
        const float4 tb = s_box[t];                      // broadcast ds_read_b128
        const float  st = (tb.z - tb.x) * (tb.w - tb.y); // shared across 6 anchors
        #pragma unroll
        for (int j = 0; j < NA; ++j) {
            const float iw = fmaxf(fminf(tb.z, Ax[j].z) - fmaxf(tb.x, Ax[j].x), 0.f);
            const float ih = fmaxf(fminf(tb.w, Ax[j].w) - fmaxf(tb.y, Ax[j].y), 0.f);
            const float n  = iw * ih;
            const float d  = sa[j] + st;
            if (n * bd[j] > bn[j] * d) { bn[j] = n; bd[j] = d; bt[j] = t; } // first-max
        }
    }

    float bce = 0.f, sl1 = 0.f, npos = 0.f;
    #pragma unroll
    for (int j = 0; j < NA; ++j) {
        const float pos = (3.f * bn[j] > bd[j]) ? 1.f : 0.f;
        bce  += sp[j] - cv[j] * pos;
        npos += pos;
        if (pos != 0.f) {
            const float4 r  = reinterpret_cast<const float4*>(reg)[base + q + j * S];
            const float4 tb = s_box[bt[j]];
            float e, ae;
            e = r.x - (tb.x - Ax[j].x); ae = fabsf(e); sl1 += (ae < 1.f) ? 0.5f * e * e : ae - 0.5f;
            e = r.y - (tb.y - Ax[j].y); ae = fabsf(e); sl1 += (ae < 1.f) ? 0.5f * e * e : ae - 0.5f;
            e = r.z - (tb.z - Ax[j].z); ae = fabsf(e); sl1 += (ae < 1.f) ? 0.5f * e * e : ae - 0.5f;
            e = r.w - (tb.w - Ax[j].w); ae = fabsf(e); sl1 += (ae < 1.f) ? 0.5f * e * e : ae - 0.5f;
        }
    }

    // deterministic block reduction: wave64 shuffle then cross-wave LDS
    for (int off = 32; off > 0; off >>= 1) {
        bce  += __shfl_down(bce,  off, 64);
        sl1  += __shfl_down(sl1,  off, 64);
        npos += __shfl_down(npos, off, 64);
    }
    __shared__ float w_bce[BLOCK / 64], w_sl1[BLOCK / 64], w_np[BLOCK / 64];
    const int lane = threadIdx.x & 63, wid = threadIdx.x >> 6;
    if (lane == 0) { w_bce[wid] = bce; w_sl1[wid] = sl1; w_np[wid] = npos; }
    __syncthreads();
    if (threadIdx.x == 0) {
        float tb_ = 0.f, ts_ = 0.f, tn_ = 0.f;
        for (int w = 0; w < BLOCK / 64; ++w) {
            tb_ += w_bce[w]; ts_ += w_sl1[w]; tn_ += w_np[w];
        }
        partials[0 * nblk + blockIdx.x] = tb_;
        partials[1 * nblk + blockIdx.x] = ts_;
        partials[2 * nblk + blockIdx.x] = tn_;
    }
}

// Final reduce: ONE wave, pure double shuffle reduction, no __syncthreads.
__global__ void __launch_bounds__(64)
rpn_final(const float* __restrict__ partials, int nblk,
          float* __restrict__ out, int BA) {
    double b = 0.0, s = 0.0, n = 0.0;
    for (int i = threadIdx.x; i < nblk; i += 64) {
        b += (double)partials[0 * nblk + i];
        s += (double)partials[1 * nblk + i];
        n += (double)partials[2 * nblk + i];
    }
    for (int off = 32; off > 0; off >>= 1) {
        b += __shfl_down(b, off, 64);
        s += __shfl_down(s, off, 64);
        n += __shfl_down(n, off, 64);
    }
    if (threadIdx.x == 0) {
        const double denom = n > 1.0 ? n : 1.0;
        const double reg_loss = (n > 0.0) ? (s / denom) : 0.0;
        out[0] = (float)(b / (double)BA);     // cls_loss (mean BCE)
        out[1] = (float)(reg_loss * 0.25);    // reg_loss / 4
    }
}

extern "C" void kernel_launch(void* const* d_in, const int* in_sizes, int n_in,
                              void* d_out, int out_size, void* d_ws, size_t ws_size,
                              hipStream_t stream) {
    const float* reg     = (const float*)d_in[0];
    const float* cls     = (const float*)d_in[1];
    const float* anchors = (const float*)d_in[2];
    const float* targets = (const float*)d_in[3];
    float* out = (float*)d_out;

    const int A = in_sizes[2] / 4;          // anchors [A,4]
    const int B = in_sizes[1] / A;          // cls [B,A]
    const int T = in_sizes[3] / (B * 4);    // targets [B,T,4]
    const int BA = B * A;
    const int nblk = (B * (A / NA)) / BLOCK; // 256 for this shape -> 1 block/CU

    float* partials = (float*)d_ws;         // SoA [3][nblk], fully overwritten every call

    rpn_main<<<nblk, BLOCK, 0, stream>>>(reg, cls, anchors, targets,
                                         partials, A, B, T, nblk);
    rpn_final<<<1, 64, 0, stream>>>(partials, nblk, out, BA);
}